// Round 2
// baseline (152.531 us; speedup 1.0000x reference)
//
#include <hip/hip_runtime.h>

#define NG   1024
#define IMH  128
#define IMW  128
#define NPIX (IMH * IMW)
#define SEGS 16
#define GPS  (NG / SEGS)   // 64 gaussians per segment

// ---------------------------------------------------------------------------
// Kernel 1: per-gaussian preprocess. Computes projected center, inverse 2D
// covariance (folded as power coefficients), SH color, validity-folded
// opacity, and a stable 64-bit depth sort key. Also zeroes the rank array.
// ---------------------------------------------------------------------------
__global__ __launch_bounds__(256) void k_pre(
    const float* __restrict__ means,
    const float* __restrict__ sh,
    const float* __restrict__ opac,
    const float* __restrict__ scales,
    const float* __restrict__ rots,
    const float* __restrict__ campos,
    const float* __restrict__ camrot,
    const float* __restrict__ thf_p,
    const float* __restrict__ nearfar,
    float4* __restrict__ p0, float4* __restrict__ p1, float* __restrict__ p2,
    unsigned long long* __restrict__ keys, int* __restrict__ rank)
{
    int i = blockIdx.x * blockDim.x + threadIdx.x;
    if (i >= NG) return;
    rank[i] = 0;

    float thf = thf_p[0];
    float fx = IMW / (2.0f * thf);
    float fy = IMH / (2.0f * thf);
    float R[9];
    #pragma unroll
    for (int k = 0; k < 9; k++) R[k] = camrot[k];
    float cp0 = campos[0], cp1 = campos[1], cp2 = campos[2];
    float near_ = nearfar[0], far_ = nearfar[1];

    float d0x = means[3 * i + 0] - cp0;
    float d0y = means[3 * i + 1] - cp1;
    float d0z = means[3 * i + 2] - cp2;

    float tx0 = R[0] * d0x + R[1] * d0y + R[2] * d0z;
    float ty0 = R[3] * d0x + R[4] * d0y + R[5] * d0z;
    float tz  = R[6] * d0x + R[7] * d0y + R[8] * d0z;

    float lim  = 1.3f * thf;
    float invz = 1.0f / tz;
    float txc  = fminf(fmaxf(tx0 * invz, -lim), lim) * tz;
    float tyc  = fminf(fmaxf(ty0 * invz, -lim), lim) * tz;

    // quaternion -> rotation
    float qr = rots[4 * i + 0], qx = rots[4 * i + 1];
    float qy = rots[4 * i + 2], qz = rots[4 * i + 3];
    float qn = rsqrtf(qr * qr + qx * qx + qy * qy + qz * qz);
    qr *= qn; qx *= qn; qy *= qn; qz *= qn;
    float Rq0 = 1.0f - 2.0f * (qy * qy + qz * qz);
    float Rq1 = 2.0f * (qx * qy - qr * qz);
    float Rq2 = 2.0f * (qx * qz + qr * qy);
    float Rq3 = 2.0f * (qx * qy + qr * qz);
    float Rq4 = 1.0f - 2.0f * (qx * qx + qz * qz);
    float Rq5 = 2.0f * (qy * qz - qr * qx);
    float Rq6 = 2.0f * (qx * qz - qr * qy);
    float Rq7 = 2.0f * (qy * qz + qr * qx);
    float Rq8 = 1.0f - 2.0f * (qx * qx + qy * qy);

    float sx = scales[3 * i + 0], sy = scales[3 * i + 1], sz = scales[3 * i + 2];
    float M0 = Rq0 * sx, M1 = Rq1 * sy, M2 = Rq2 * sz;
    float M3 = Rq3 * sx, M4 = Rq4 * sy, M5 = Rq5 * sz;
    float M6 = Rq6 * sx, M7 = Rq7 * sy, M8 = Rq8 * sz;

    float c00 = M0 * M0 + M1 * M1 + M2 * M2;
    float c01 = M0 * M3 + M1 * M4 + M2 * M5;
    float c02 = M0 * M6 + M1 * M7 + M2 * M8;
    float c11 = M3 * M3 + M4 * M4 + M5 * M5;
    float c12 = M3 * M6 + M4 * M7 + M5 * M8;
    float c22 = M6 * M6 + M7 * M7 + M8 * M8;

    float z2  = tz * tz;
    float J00 = fx * invz, J02 = -fx * txc / z2;
    float J11 = fy * invz, J12 = -fy * tyc / z2;

    // T2 = J @ camrot
    float T00 = J00 * R[0] + J02 * R[6];
    float T01 = J00 * R[1] + J02 * R[7];
    float T02 = J00 * R[2] + J02 * R[8];
    float T10 = J11 * R[3] + J12 * R[6];
    float T11 = J11 * R[4] + J12 * R[7];
    float T12 = J11 * R[5] + J12 * R[8];

    // cov2 = T2 cov3 T2^T
    float v00 = T00 * c00 + T01 * c01 + T02 * c02;
    float v01 = T00 * c01 + T01 * c11 + T02 * c12;
    float v02 = T00 * c02 + T01 * c12 + T02 * c22;
    float v10 = T10 * c00 + T11 * c01 + T12 * c02;
    float v11 = T10 * c01 + T11 * c11 + T12 * c12;
    float v12 = T10 * c02 + T11 * c12 + T12 * c22;

    float a = v00 * T00 + v01 * T01 + v02 * T02 + 0.3f;
    float b = v00 * T10 + v01 * T11 + v02 * T12;
    float c = v10 * T10 + v11 * T11 + v12 * T12 + 0.3f;

    float det    = a * c - b * b;
    float invdet = 1.0f / det;
    float conA = c * invdet, conB = -b * invdet, conC = a * invdet;

    float mx = fx * tx0 * invz + (IMW - 1) * 0.5f;
    float my = fy * ty0 * invz + (IMH - 1) * 0.5f;

    // SH evaluation (degree 3, 16 coeffs)
    float dn = rsqrtf(d0x * d0x + d0y * d0y + d0z * d0z);
    float x = d0x * dn, y = d0y * dn, z = d0z * dn;
    float xx = x * x, yy = y * y, zz = z * z;
    float xy = x * y, yz = y * z, xz = x * z;

    float basis[16];
    basis[0]  = 0.28209479177387814f;
    basis[1]  = -0.4886025119029199f * y;
    basis[2]  =  0.4886025119029199f * z;
    basis[3]  = -0.4886025119029199f * x;
    basis[4]  =  1.0925484305920792f * xy;
    basis[5]  = -1.0925484305920792f * yz;
    basis[6]  =  0.31539156525252005f * (2.0f * zz - xx - yy);
    basis[7]  = -1.0925484305920792f * xz;
    basis[8]  =  0.5462742152960396f * (xx - yy);
    basis[9]  = -0.5900435899266435f * y * (3.0f * xx - yy);
    basis[10] =  2.890611442640554f * xy * z;
    basis[11] = -0.4570457994644658f * y * (4.0f * zz - xx - yy);
    basis[12] =  0.3731763325901154f * z * (2.0f * zz - 3.0f * xx - 3.0f * yy);
    basis[13] = -0.4570457994644658f * x * (4.0f * zz - xx - yy);
    basis[14] =  1.445305721320277f * z * (xx - yy);
    basis[15] = -0.5900435899266435f * x * (xx - 3.0f * yy);

    const float* shp = sh + i * 48;
    float col[3];
    #pragma unroll
    for (int ch = 0; ch < 3; ch++) {
        float res = 0.0f;
        #pragma unroll
        for (int k = 0; k < 16; k++) res += basis[k] * shp[k * 3 + ch];
        col[ch] = fmaxf(res + 0.5f, 0.0f);
    }

    bool valid = (tz > near_) && (tz < far_) && (det > 0.0f);
    float op = valid ? opac[i] : 0.0f;

    // power = A2*dx^2 + B2*dx*dy + C2*dy^2, A2=-0.5conA, B2=-conB, C2=-0.5conC
    p0[i] = make_float4(mx, my, -0.5f * conA, -conB);
    p1[i] = make_float4(-0.5f * conC, op, col[0], col[1]);
    p2[i] = col[2];

    // stable ascending sort key: order-preserving float bits + index tiebreak
    unsigned u = __float_as_uint(tz);
    u = (u & 0x80000000u) ? ~u : (u | 0x80000000u);
    keys[i] = ((unsigned long long)u << 32) | (unsigned)i;
}

// ---------------------------------------------------------------------------
// Kernel 2: rank sort — rank[i] = #{j : key[j] < key[i]} (keys unique).
// 64 blocks = 8 i-chunks x 8 j-chunks; partial counts via atomicAdd.
// ---------------------------------------------------------------------------
__global__ __launch_bounds__(128) void k_rank(
    const unsigned long long* __restrict__ keys, int* __restrict__ rank)
{
    int ib = blockIdx.x & 7;
    int jb = blockIdx.x >> 3;
    int i = ib * 128 + threadIdx.x;
    unsigned long long ki = keys[i];
    int j0 = jb * 128;
    int cnt = 0;
    #pragma unroll 8
    for (int j = 0; j < 128; j++) cnt += (keys[j0 + j] < ki) ? 1 : 0;
    atomicAdd(&rank[i], cnt);
}

// ---------------------------------------------------------------------------
// Kernel 3: gather into depth-sorted SoA
// ---------------------------------------------------------------------------
__global__ __launch_bounds__(256) void k_gather(
    const float4* __restrict__ p0, const float4* __restrict__ p1,
    const float* __restrict__ p2, const int* __restrict__ rank,
    float4* __restrict__ s0, float4* __restrict__ s1, float* __restrict__ s2)
{
    int i = blockIdx.x * blockDim.x + threadIdx.x;
    if (i >= NG) return;
    int r = rank[i];
    s0[r] = p0[i];
    s1[r] = p1[i];
    s2[r] = p2[i];
}

// ---------------------------------------------------------------------------
// Kernel 4: per-pixel compositing. 16 segments of 64 sorted gaussians per
// pixel; each thread composites one segment locally (T, C), then a 4-step
// ordered shuffle butterfly combines segments: (T,C)+(T',C') = (TT', C+T C').
// ---------------------------------------------------------------------------
__global__ __launch_bounds__(256) void k_comp(
    const float4* __restrict__ s0, const float4* __restrict__ s1,
    const float* __restrict__ s2, const float* __restrict__ bg,
    float* __restrict__ out)
{
    int tid = threadIdx.x;
    int seg = tid & (SEGS - 1);
    int pix = blockIdx.x * (256 / SEGS) + (tid >> 4);
    float fpx = (float)(pix & (IMW - 1));
    float fpy = (float)(pix >> 7);

    float T = 1.0f, cr = 0.0f, cg = 0.0f, cb = 0.0f;
    int base = seg * GPS;

    #pragma unroll 4
    for (int k = 0; k < GPS; k++) {
        float4 q0 = s0[base + k];   // mx, my, A2, B2
        float4 q1 = s1[base + k];   // C2, op, col_r, col_g
        float  q2 = s2[base + k];   // col_b
        float dx = fpx - q0.x;
        float dy = fpy - q0.y;
        float pw = fmaf(dx, fmaf(q0.z, dx, q0.w * dy), q1.x * (dy * dy));
        float al = q1.y * __expf(pw);
        al = fminf(al, 0.99f);
        bool ok = (pw <= 0.0f) && (al >= (1.0f / 255.0f));
        al = ok ? al : 0.0f;
        float w = al * T;
        cr = fmaf(w, q1.z, cr);
        cg = fmaf(w, q1.w, cg);
        cb = fmaf(w, q2, cb);
        T = fmaf(-al, T, T);
    }

    // ordered butterfly combine across 16 segments (within a wave)
    #pragma unroll
    for (int s = 1; s < SEGS; s <<= 1) {
        float oT = __shfl_xor(T, s, 64);
        float oR = __shfl_xor(cr, s, 64);
        float oG = __shfl_xor(cg, s, 64);
        float oB = __shfl_xor(cb, s, 64);
        if (seg & s) {  // I'm the later (deeper) half: other is in front
            cr = oR + oT * cr;
            cg = oG + oT * cg;
            cb = oB + oT * cb;
            T = oT * T;
        } else {        // I'm the front half
            cr = cr + T * oR;
            cg = cg + T * oG;
            cb = cb + T * oB;
            T = T * oT;
        }
    }

    if (seg == 0) {
        out[0 * NPIX + pix] = cr + T * bg[0];
        out[1 * NPIX + pix] = cg + T * bg[1];
        out[2 * NPIX + pix] = cb + T * bg[2];
    }
}

// ---------------------------------------------------------------------------
extern "C" void kernel_launch(void* const* d_in, const int* in_sizes, int n_in,
                              void* d_out, int out_size, void* d_ws, size_t ws_size,
                              hipStream_t stream)
{
    (void)in_sizes; (void)n_in; (void)out_size; (void)ws_size;

    const float* means   = (const float*)d_in[0];
    const float* sh      = (const float*)d_in[1];
    const float* opac    = (const float*)d_in[2];
    const float* scales  = (const float*)d_in[3];
    const float* rots    = (const float*)d_in[4];
    const float* campos  = (const float*)d_in[5];
    const float* camrot  = (const float*)d_in[6];
    const float* thf     = (const float*)d_in[7];
    const float* bg      = (const float*)d_in[8];
    const float* nearfar = (const float*)d_in[9];

    char* ws = (char*)d_ws;
    float4* p0 = (float4*)(ws + 0);
    float4* p1 = (float4*)(ws + 16384);
    float4* s0 = (float4*)(ws + 32768);
    float4* s1 = (float4*)(ws + 49152);
    float*  p2 = (float*)(ws + 65536);
    float*  s2 = (float*)(ws + 69632);
    unsigned long long* keys = (unsigned long long*)(ws + 73728);
    int* rank = (int*)(ws + 81920);

    k_pre<<<4, 256, 0, stream>>>(means, sh, opac, scales, rots, campos, camrot,
                                 thf, nearfar, p0, p1, p2, keys, rank);
    k_rank<<<64, 128, 0, stream>>>(keys, rank);
    k_gather<<<4, 256, 0, stream>>>(p0, p1, p2, rank, s0, s1, s2);
    k_comp<<<NPIX * SEGS / 256, 256, 0, stream>>>(s0, s1, s2, bg,
                                                  (float*)d_out);
}

// Round 3
// 106.700 us; speedup vs baseline: 1.4295x; 1.4295x over previous
//
#include <hip/hip_runtime.h>

#define NG   1024
#define IMH  128
#define IMW  128
#define NPIX (IMH * IMW)
#define SEGS 16
#define GPS  (NG / SEGS)   // 64 gaussians per segment

// ---------------------------------------------------------------------------
// Kernel 1: per-gaussian preprocess -> packed params + stable sort key.
// ---------------------------------------------------------------------------
__global__ __launch_bounds__(64) void k_pre(
    const float* __restrict__ means,
    const float* __restrict__ sh,
    const float* __restrict__ opac,
    const float* __restrict__ scales,
    const float* __restrict__ rots,
    const float* __restrict__ campos,
    const float* __restrict__ camrot,
    const float* __restrict__ thf_p,
    const float* __restrict__ nearfar,
    float4* __restrict__ p0, float4* __restrict__ p1, float* __restrict__ p2,
    unsigned long long* __restrict__ keys)
{
    int i = blockIdx.x * blockDim.x + threadIdx.x;
    if (i >= NG) return;

    float thf = thf_p[0];
    float fx = IMW / (2.0f * thf);
    float fy = IMH / (2.0f * thf);
    float R[9];
    #pragma unroll
    for (int k = 0; k < 9; k++) R[k] = camrot[k];
    float cp0 = campos[0], cp1 = campos[1], cp2 = campos[2];
    float near_ = nearfar[0], far_ = nearfar[1];

    float d0x = means[3 * i + 0] - cp0;
    float d0y = means[3 * i + 1] - cp1;
    float d0z = means[3 * i + 2] - cp2;

    float tx0 = R[0] * d0x + R[1] * d0y + R[2] * d0z;
    float ty0 = R[3] * d0x + R[4] * d0y + R[5] * d0z;
    float tz  = R[6] * d0x + R[7] * d0y + R[8] * d0z;

    float lim  = 1.3f * thf;
    float invz = 1.0f / tz;
    float txc  = fminf(fmaxf(tx0 * invz, -lim), lim) * tz;
    float tyc  = fminf(fmaxf(ty0 * invz, -lim), lim) * tz;

    // quaternion -> rotation
    float qr = rots[4 * i + 0], qx = rots[4 * i + 1];
    float qy = rots[4 * i + 2], qz = rots[4 * i + 3];
    float qn = rsqrtf(qr * qr + qx * qx + qy * qy + qz * qz);
    qr *= qn; qx *= qn; qy *= qn; qz *= qn;
    float Rq0 = 1.0f - 2.0f * (qy * qy + qz * qz);
    float Rq1 = 2.0f * (qx * qy - qr * qz);
    float Rq2 = 2.0f * (qx * qz + qr * qy);
    float Rq3 = 2.0f * (qx * qy + qr * qz);
    float Rq4 = 1.0f - 2.0f * (qx * qx + qz * qz);
    float Rq5 = 2.0f * (qy * qz - qr * qx);
    float Rq6 = 2.0f * (qx * qz - qr * qy);
    float Rq7 = 2.0f * (qy * qz + qr * qx);
    float Rq8 = 1.0f - 2.0f * (qx * qx + qy * qy);

    float sx = scales[3 * i + 0], sy = scales[3 * i + 1], sz = scales[3 * i + 2];
    float M0 = Rq0 * sx, M1 = Rq1 * sy, M2 = Rq2 * sz;
    float M3 = Rq3 * sx, M4 = Rq4 * sy, M5 = Rq5 * sz;
    float M6 = Rq6 * sx, M7 = Rq7 * sy, M8 = Rq8 * sz;

    float c00 = M0 * M0 + M1 * M1 + M2 * M2;
    float c01 = M0 * M3 + M1 * M4 + M2 * M5;
    float c02 = M0 * M6 + M1 * M7 + M2 * M8;
    float c11 = M3 * M3 + M4 * M4 + M5 * M5;
    float c12 = M3 * M6 + M4 * M7 + M5 * M8;
    float c22 = M6 * M6 + M7 * M7 + M8 * M8;

    float z2  = tz * tz;
    float J00 = fx * invz, J02 = -fx * txc / z2;
    float J11 = fy * invz, J12 = -fy * tyc / z2;

    float T00 = J00 * R[0] + J02 * R[6];
    float T01 = J00 * R[1] + J02 * R[7];
    float T02 = J00 * R[2] + J02 * R[8];
    float T10 = J11 * R[3] + J12 * R[6];
    float T11 = J11 * R[4] + J12 * R[7];
    float T12 = J11 * R[5] + J12 * R[8];

    float v00 = T00 * c00 + T01 * c01 + T02 * c02;
    float v01 = T00 * c01 + T01 * c11 + T02 * c12;
    float v02 = T00 * c02 + T01 * c12 + T02 * c22;
    float v10 = T10 * c00 + T11 * c01 + T12 * c02;
    float v11 = T10 * c01 + T11 * c11 + T12 * c12;
    float v12 = T10 * c02 + T11 * c12 + T12 * c22;

    float a = v00 * T00 + v01 * T01 + v02 * T02 + 0.3f;
    float b = v00 * T10 + v01 * T11 + v02 * T12;
    float c = v10 * T10 + v11 * T11 + v12 * T12 + 0.3f;

    float det    = a * c - b * b;
    float invdet = 1.0f / det;
    float conA = c * invdet, conB = -b * invdet, conC = a * invdet;

    float mx = fx * tx0 * invz + (IMW - 1) * 0.5f;
    float my = fy * ty0 * invz + (IMH - 1) * 0.5f;

    // SH (degree 3)
    float dn = rsqrtf(d0x * d0x + d0y * d0y + d0z * d0z);
    float x = d0x * dn, y = d0y * dn, z = d0z * dn;
    float xx = x * x, yy = y * y, zz = z * z;
    float xy = x * y, yz = y * z, xz = x * z;

    float basis[16];
    basis[0]  = 0.28209479177387814f;
    basis[1]  = -0.4886025119029199f * y;
    basis[2]  =  0.4886025119029199f * z;
    basis[3]  = -0.4886025119029199f * x;
    basis[4]  =  1.0925484305920792f * xy;
    basis[5]  = -1.0925484305920792f * yz;
    basis[6]  =  0.31539156525252005f * (2.0f * zz - xx - yy);
    basis[7]  = -1.0925484305920792f * xz;
    basis[8]  =  0.5462742152960396f * (xx - yy);
    basis[9]  = -0.5900435899266435f * y * (3.0f * xx - yy);
    basis[10] =  2.890611442640554f * xy * z;
    basis[11] = -0.4570457994644658f * y * (4.0f * zz - xx - yy);
    basis[12] =  0.3731763325901154f * z * (2.0f * zz - 3.0f * xx - 3.0f * yy);
    basis[13] = -0.4570457994644658f * x * (4.0f * zz - xx - yy);
    basis[14] =  1.445305721320277f * z * (xx - yy);
    basis[15] = -0.5900435899266435f * x * (xx - 3.0f * yy);

    const float* shp = sh + i * 48;
    float col[3];
    #pragma unroll
    for (int ch = 0; ch < 3; ch++) {
        float res = 0.0f;
        #pragma unroll
        for (int k = 0; k < 16; k++) res += basis[k] * shp[k * 3 + ch];
        col[ch] = fmaxf(res + 0.5f, 0.0f);
    }

    bool valid = (tz > near_) && (tz < far_) && (det > 0.0f);
    float op = valid ? opac[i] : 0.0f;

    p0[i] = make_float4(mx, my, -0.5f * conA, -conB);
    p1[i] = make_float4(-0.5f * conC, op, col[0], col[1]);
    p2[i] = col[2];

    unsigned u = __float_as_uint(tz);
    u = (u & 0x80000000u) ? ~u : (u | 0x80000000u);
    keys[i] = ((unsigned long long)u << 32) | (unsigned)i;
}

// ---------------------------------------------------------------------------
// Kernel 2: fused rank-sort + gather. Keys staged in LDS; each thread ranks
// its gaussian against all 1024 (broadcast reads), then scatters to slot r.
// ---------------------------------------------------------------------------
__global__ __launch_bounds__(256) void k_sortg(
    const unsigned long long* __restrict__ keys,
    const float4* __restrict__ p0, const float4* __restrict__ p1,
    const float* __restrict__ p2,
    float4* __restrict__ s0, float4* __restrict__ s1, float* __restrict__ s2)
{
    __shared__ unsigned long long lk[NG];
    int t = threadIdx.x;
    #pragma unroll
    for (int j = 0; j < 4; j++) lk[j * 256 + t] = keys[j * 256 + t];
    __syncthreads();

    int i = blockIdx.x * 256 + t;
    unsigned long long ki = lk[i];
    int r = 0;
    #pragma unroll 8
    for (int j = 0; j < NG; j++) r += (lk[j] < ki) ? 1 : 0;

    s0[r] = p0[i];
    s1[r] = p1[i];
    s2[r] = p2[i];
}

// ---------------------------------------------------------------------------
// Kernel 3: compositing. Block = 1024 threads = 16 waves, 64 pixels/block.
// Wave s composites segment s (64 sorted gaussians) for all 64 pixels
// (lane = pixel), so the gaussian index is WAVE-UNIFORM -> scalar broadcast
// loads, no per-lane VMEM in the hot loop. Ordered combine via LDS.
// ---------------------------------------------------------------------------
__global__ __launch_bounds__(1024) void k_comp(
    const float4* __restrict__ s0, const float4* __restrict__ s1,
    const float* __restrict__ s2, const float* __restrict__ bg,
    float* __restrict__ out)
{
    __shared__ float4 red[SEGS * 64];   // (cr,cg,cb,T) per seg x pixel

    int tid  = threadIdx.x;
    int lane = tid & 63;                                   // pixel in block
    int seg  = __builtin_amdgcn_readfirstlane(tid >> 6);   // wave id 0..15
    int pix  = blockIdx.x * 64 + lane;
    float fpx = (float)(pix & (IMW - 1));
    float fpy = (float)(pix >> 7);

    float T = 1.0f, cr = 0.0f, cg = 0.0f, cb = 0.0f;
    int base = seg * GPS;

    #pragma unroll 4
    for (int k = 0; k < GPS; k++) {
        float4 q0 = s0[base + k];   // mx, my, A2, B2   (uniform -> s_load)
        float4 q1 = s1[base + k];   // C2, op, col_r, col_g
        float  q2 = s2[base + k];   // col_b
        float dx = fpx - q0.x;
        float dy = fpy - q0.y;
        float pw = fmaf(dx, fmaf(q0.z, dx, q0.w * dy), q1.x * (dy * dy));
        float al = q1.y * __expf(pw);
        al = fminf(al, 0.99f);
        bool ok = (pw <= 0.0f) && (al >= (1.0f / 255.0f));
        al = ok ? al : 0.0f;
        float w = al * T;
        cr = fmaf(w, q1.z, cr);
        cg = fmaf(w, q1.w, cg);
        cb = fmaf(w, q2, cb);
        T = fmaf(-al, T, T);
    }

    red[seg * 64 + lane] = make_float4(cr, cg, cb, T);
    __syncthreads();

    if (tid < 64) {
        float Tt = 1.0f, r = 0.0f, g = 0.0f, b = 0.0f;
        #pragma unroll
        for (int s = 0; s < SEGS; s++) {
            float4 v = red[s * 64 + tid];
            r = fmaf(Tt, v.x, r);
            g = fmaf(Tt, v.y, g);
            b = fmaf(Tt, v.z, b);
            Tt *= v.w;
        }
        int p = blockIdx.x * 64 + tid;
        out[0 * NPIX + p] = r + Tt * bg[0];
        out[1 * NPIX + p] = g + Tt * bg[1];
        out[2 * NPIX + p] = b + Tt * bg[2];
    }
}

// ---------------------------------------------------------------------------
extern "C" void kernel_launch(void* const* d_in, const int* in_sizes, int n_in,
                              void* d_out, int out_size, void* d_ws, size_t ws_size,
                              hipStream_t stream)
{
    (void)in_sizes; (void)n_in; (void)out_size; (void)ws_size;

    const float* means   = (const float*)d_in[0];
    const float* sh      = (const float*)d_in[1];
    const float* opac    = (const float*)d_in[2];
    const float* scales  = (const float*)d_in[3];
    const float* rots    = (const float*)d_in[4];
    const float* campos  = (const float*)d_in[5];
    const float* camrot  = (const float*)d_in[6];
    const float* thf     = (const float*)d_in[7];
    const float* bg      = (const float*)d_in[8];
    const float* nearfar = (const float*)d_in[9];

    char* ws = (char*)d_ws;
    float4* p0 = (float4*)(ws + 0);
    float4* p1 = (float4*)(ws + 16384);
    float4* s0 = (float4*)(ws + 32768);
    float4* s1 = (float4*)(ws + 49152);
    float*  p2 = (float*)(ws + 65536);
    float*  s2 = (float*)(ws + 69632);
    unsigned long long* keys = (unsigned long long*)(ws + 73728);

    k_pre<<<16, 64, 0, stream>>>(means, sh, opac, scales, rots, campos, camrot,
                                 thf, nearfar, p0, p1, p2, keys);
    k_sortg<<<4, 256, 0, stream>>>(keys, p0, p1, p2, s0, s1, s2);
    k_comp<<<NPIX / 64, 1024, 0, stream>>>(s0, s1, s2, bg, (float*)d_out);
}

// Round 4
// 87.203 us; speedup vs baseline: 1.7491x; 1.2236x over previous
//
#include <hip/hip_runtime.h>

#define NG   1024
#define IMH  128
#define IMW  128
#define NPIX (IMH * IMW)
#define SEGS 16

// ---------------------------------------------------------------------------
// Kernel 1: fused preprocess + stable depth sort (rank sort) + scatter.
// 16 blocks x 256 threads. Per block: (A) all 1024 sort keys cooperatively
// into LDS; (B) rank of this block's 64 gaussians, compare-loop split 4 ways
// across the 4 waves; (C) wave 0 fully preprocesses the block's 64 gaussians
// (projection, 2D cov, SH color, conservative cull radii) and scatters to the
// depth-sorted SoA slot.
// ---------------------------------------------------------------------------
__global__ __launch_bounds__(256) void k_prep(
    const float* __restrict__ means,
    const float* __restrict__ sh,
    const float* __restrict__ opac,
    const float* __restrict__ scales,
    const float* __restrict__ rots,
    const float* __restrict__ campos,
    const float* __restrict__ camrot,
    const float* __restrict__ thf_p,
    const float* __restrict__ nearfar,
    float4* __restrict__ g0, float4* __restrict__ g1, float4* __restrict__ g2)
{
    __shared__ unsigned long long lk[NG];
    __shared__ int prank[4 * 64];

    int t = threadIdx.x;
    int b = blockIdx.x;

    float thf = thf_p[0];
    float R[9];
    #pragma unroll
    for (int k = 0; k < 9; k++) R[k] = camrot[k];
    float cp0 = campos[0], cp1 = campos[1], cp2 = campos[2];
    float near_ = nearfar[0], far_ = nearfar[1];

    // --- stage A: all 1024 keys (4 per thread), stable (idx in low bits)
    #pragma unroll
    for (int j = 0; j < 4; j++) {
        int g = j * 256 + t;
        float dx = means[3 * g + 0] - cp0;
        float dy = means[3 * g + 1] - cp1;
        float dz = means[3 * g + 2] - cp2;
        float tzk = R[6] * dx + R[7] * dy + R[8] * dz;
        unsigned u = __float_as_uint(tzk);
        u = (u & 0x80000000u) ? ~u : (u | 0x80000000u);
        lk[g] = ((unsigned long long)u << 32) | (unsigned)g;
    }
    __syncthreads();

    // --- stage B: partial ranks; thread t handles gaussian b*64+(t&63),
    // compare-range chunk (t>>6)*256..+256
    int li    = t & 63;
    int chunk = t >> 6;
    int gi    = b * 64 + li;
    unsigned long long ki = lk[gi];
    int cnt = 0;
    int j0 = chunk * 256;
    #pragma unroll 8
    for (int j = 0; j < 256; j++) cnt += (lk[j0 + j] < ki) ? 1 : 0;
    prank[chunk * 64 + li] = cnt;
    __syncthreads();

    // --- stage C: full preprocess by wave 0 only (one gaussian per lane)
    if (t < 64) {
        int i = b * 64 + t;
        float fx = IMW / (2.0f * thf);
        float fy = IMH / (2.0f * thf);

        float d0x = means[3 * i + 0] - cp0;
        float d0y = means[3 * i + 1] - cp1;
        float d0z = means[3 * i + 2] - cp2;

        float tx0 = R[0] * d0x + R[1] * d0y + R[2] * d0z;
        float ty0 = R[3] * d0x + R[4] * d0y + R[5] * d0z;
        float tz  = R[6] * d0x + R[7] * d0y + R[8] * d0z;

        float lim  = 1.3f * thf;
        float invz = 1.0f / tz;
        float txc  = fminf(fmaxf(tx0 * invz, -lim), lim) * tz;
        float tyc  = fminf(fmaxf(ty0 * invz, -lim), lim) * tz;

        float qr = rots[4 * i + 0], qx = rots[4 * i + 1];
        float qy = rots[4 * i + 2], qz = rots[4 * i + 3];
        float qn = rsqrtf(qr * qr + qx * qx + qy * qy + qz * qz);
        qr *= qn; qx *= qn; qy *= qn; qz *= qn;
        float Rq0 = 1.0f - 2.0f * (qy * qy + qz * qz);
        float Rq1 = 2.0f * (qx * qy - qr * qz);
        float Rq2 = 2.0f * (qx * qz + qr * qy);
        float Rq3 = 2.0f * (qx * qy + qr * qz);
        float Rq4 = 1.0f - 2.0f * (qx * qx + qz * qz);
        float Rq5 = 2.0f * (qy * qz - qr * qx);
        float Rq6 = 2.0f * (qx * qz - qr * qy);
        float Rq7 = 2.0f * (qy * qz + qr * qx);
        float Rq8 = 1.0f - 2.0f * (qx * qx + qy * qy);

        float sx = scales[3 * i + 0], sy = scales[3 * i + 1], sz = scales[3 * i + 2];
        float M0 = Rq0 * sx, M1 = Rq1 * sy, M2 = Rq2 * sz;
        float M3 = Rq3 * sx, M4 = Rq4 * sy, M5 = Rq5 * sz;
        float M6 = Rq6 * sx, M7 = Rq7 * sy, M8 = Rq8 * sz;

        float c00 = M0 * M0 + M1 * M1 + M2 * M2;
        float c01 = M0 * M3 + M1 * M4 + M2 * M5;
        float c02 = M0 * M6 + M1 * M7 + M2 * M8;
        float c11 = M3 * M3 + M4 * M4 + M5 * M5;
        float c12 = M3 * M6 + M4 * M7 + M5 * M8;
        float c22 = M6 * M6 + M7 * M7 + M8 * M8;

        float z2  = tz * tz;
        float J00 = fx * invz, J02 = -fx * txc / z2;
        float J11 = fy * invz, J12 = -fy * tyc / z2;

        float T00 = J00 * R[0] + J02 * R[6];
        float T01 = J00 * R[1] + J02 * R[7];
        float T02 = J00 * R[2] + J02 * R[8];
        float T10 = J11 * R[3] + J12 * R[6];
        float T11 = J11 * R[4] + J12 * R[7];
        float T12 = J11 * R[5] + J12 * R[8];

        float v00 = T00 * c00 + T01 * c01 + T02 * c02;
        float v01 = T00 * c01 + T01 * c11 + T02 * c12;
        float v02 = T00 * c02 + T01 * c12 + T02 * c22;
        float v10 = T10 * c00 + T11 * c01 + T12 * c02;
        float v11 = T10 * c01 + T11 * c11 + T12 * c12;
        float v12 = T10 * c02 + T11 * c12 + T12 * c22;

        float a = v00 * T00 + v01 * T01 + v02 * T02 + 0.3f;
        float bb = v00 * T10 + v01 * T11 + v02 * T12;
        float c = v10 * T10 + v11 * T11 + v12 * T12 + 0.3f;

        float det    = a * c - bb * bb;
        float invdet = 1.0f / det;
        float conA = c * invdet, conB = -bb * invdet, conC = a * invdet;

        float mx = fx * tx0 * invz + (IMW - 1) * 0.5f;
        float my = fy * ty0 * invz + (IMH - 1) * 0.5f;

        // SH (degree 3)
        float dn = rsqrtf(d0x * d0x + d0y * d0y + d0z * d0z);
        float x = d0x * dn, y = d0y * dn, z = d0z * dn;
        float xx = x * x, yy = y * y, zz = z * z;
        float xy = x * y, yz = y * z, xz = x * z;

        float basis[16];
        basis[0]  = 0.28209479177387814f;
        basis[1]  = -0.4886025119029199f * y;
        basis[2]  =  0.4886025119029199f * z;
        basis[3]  = -0.4886025119029199f * x;
        basis[4]  =  1.0925484305920792f * xy;
        basis[5]  = -1.0925484305920792f * yz;
        basis[6]  =  0.31539156525252005f * (2.0f * zz - xx - yy);
        basis[7]  = -1.0925484305920792f * xz;
        basis[8]  =  0.5462742152960396f * (xx - yy);
        basis[9]  = -0.5900435899266435f * y * (3.0f * xx - yy);
        basis[10] =  2.890611442640554f * xy * z;
        basis[11] = -0.4570457994644658f * y * (4.0f * zz - xx - yy);
        basis[12] =  0.3731763325901154f * z * (2.0f * zz - 3.0f * xx - 3.0f * yy);
        basis[13] = -0.4570457994644658f * x * (4.0f * zz - xx - yy);
        basis[14] =  1.445305721320277f * z * (xx - yy);
        basis[15] = -0.5900435899266435f * x * (xx - 3.0f * yy);

        const float* shp = sh + i * 48;
        float col[3];
        #pragma unroll
        for (int ch = 0; ch < 3; ch++) {
            float res = 0.0f;
            #pragma unroll
            for (int k = 0; k < 16; k++) res += basis[k] * shp[k * 3 + ch];
            col[ch] = fmaxf(res + 0.5f, 0.0f);
        }

        bool valid = (tz > near_) && (tz < far_) && (det > 0.0f);
        float op = valid ? opac[i] : 0.0f;

        // conservative cull radii: alpha >= 1/255 requires
        // d^T Sigma'^-1 d <= s2 = 2 ln(255*op)  ->  |dx|<=sqrt(s2*a), |dy|<=sqrt(s2*c)
        float rx, ry;
        if (op >= (1.0f / 255.0f)) {
            float s2 = 2.0f * logf(255.0f * op);
            rx = sqrtf(s2 * a) + 1e-3f;
            ry = sqrtf(s2 * c) + 1e-3f;
        } else {
            rx = -1.0f; ry = -1.0f;   // never intersects any tile
        }

        int r = prank[0 * 64 + t] + prank[1 * 64 + t] +
                prank[2 * 64 + t] + prank[3 * 64 + t];

        g0[r] = make_float4(mx, my, rx, ry);
        g1[r] = make_float4(-0.5f * conA, -conB, -0.5f * conC, op);
        g2[r] = make_float4(col[0], col[1], col[2], 0.0f);
    }
}

// ---------------------------------------------------------------------------
// Kernel 2: tile compositing. Grid = 256 blocks (16x16 tiles of 8x8 px),
// block = 1024 threads = 16 waves. Phase 1: each thread AABB-culls one
// sorted gaussian; order-preserving ballot compaction copies survivor params
// into LDS. Phase 2: wave s composites contiguous survivor segment s for the
// tile's 64 pixels (lane = pixel) with wave-uniform broadcast LDS reads.
// Phase 3: ordered 16-segment combine in LDS, write out.
// ---------------------------------------------------------------------------
__global__ __launch_bounds__(1024) void k_comp(
    const float4* __restrict__ g0, const float4* __restrict__ g1,
    const float4* __restrict__ g2, const float* __restrict__ bg,
    float* __restrict__ out)
{
    __shared__ float4 lA[NG];        // mx, my, A2, B2
    __shared__ float4 lB[NG];        // C2, op, col_r, col_g
    __shared__ float  lC[NG];        // col_b
    __shared__ float4 red[SEGS * 64];
    __shared__ int wcnt[16];

    int t    = threadIdx.x;
    int wid  = t >> 6;
    int lane = t & 63;
    int bx = blockIdx.x & 15, by = blockIdx.x >> 4;
    float x0 = (float)(bx * 8), y0 = (float)(by * 8);

    // --- phase 1: cull + order-preserving compaction
    float4 c0 = g0[t];
    bool surv = (c0.z >= 0.0f) &&
                (c0.x + c0.z >= x0) && (c0.x - c0.z <= x0 + 7.0f) &&
                (c0.y + c0.w >= y0) && (c0.y - c0.w <= y0 + 7.0f);
    unsigned long long m = __ballot(surv);
    if (lane == 0) wcnt[wid] = __popcll(m);
    __syncthreads();

    int pre = 0, M = 0;
    #pragma unroll
    for (int w = 0; w < 16; w++) {
        int cw = wcnt[w];
        M += cw;
        if (w < wid) pre += cw;
    }
    if (surv) {
        int pos = pre + __popcll(m & ((1ull << lane) - 1ull));
        float4 c1 = g1[t];
        float4 c2 = g2[t];
        lA[pos] = make_float4(c0.x, c0.y, c1.x, c1.y);
        lB[pos] = make_float4(c1.z, c1.w, c2.x, c2.y);
        lC[pos] = c2.z;
    }
    __syncthreads();

    // --- phase 2: composite segment (wave-uniform bounds & addresses)
    M = __builtin_amdgcn_readfirstlane(M);
    int len = (M + SEGS - 1) / SEGS;
    int seg = __builtin_amdgcn_readfirstlane(wid);
    int ks  = seg * len;
    int ke  = min(M, ks + len);

    float fpx = x0 + (float)(lane & 7);
    float fpy = y0 + (float)(lane >> 3);

    float T = 1.0f, cr = 0.0f, cg = 0.0f, cb = 0.0f;
    for (int k = ks; k < ke; k++) {
        float4 qA = lA[k];
        float4 qB = lB[k];
        float  qc = lC[k];
        float dx = fpx - qA.x;
        float dy = fpy - qA.y;
        float pw = fmaf(dx, fmaf(qA.z, dx, qA.w * dy), qB.x * (dy * dy));
        float al = qB.y * __expf(pw);
        al = fminf(al, 0.99f);
        bool ok = (pw <= 0.0f) && (al >= (1.0f / 255.0f));
        al = ok ? al : 0.0f;
        float w = al * T;
        cr = fmaf(w, qB.z, cr);
        cg = fmaf(w, qB.w, cg);
        cb = fmaf(w, qc, cb);
        T = fmaf(-al, T, T);
    }

    red[seg * 64 + lane] = make_float4(cr, cg, cb, T);
    __syncthreads();

    // --- phase 3: ordered combine + store
    if (t < 64) {
        float Tt = 1.0f, r = 0.0f, g = 0.0f, b = 0.0f;
        #pragma unroll
        for (int s = 0; s < SEGS; s++) {
            float4 v = red[s * 64 + t];
            r = fmaf(Tt, v.x, r);
            g = fmaf(Tt, v.y, g);
            b = fmaf(Tt, v.z, b);
            Tt *= v.w;
        }
        int pix = (by * 8 + (t >> 3)) * IMW + bx * 8 + (t & 7);
        out[0 * NPIX + pix] = r + Tt * bg[0];
        out[1 * NPIX + pix] = g + Tt * bg[1];
        out[2 * NPIX + pix] = b + Tt * bg[2];
    }
}

// ---------------------------------------------------------------------------
extern "C" void kernel_launch(void* const* d_in, const int* in_sizes, int n_in,
                              void* d_out, int out_size, void* d_ws, size_t ws_size,
                              hipStream_t stream)
{
    (void)in_sizes; (void)n_in; (void)out_size; (void)ws_size;

    const float* means   = (const float*)d_in[0];
    const float* sh      = (const float*)d_in[1];
    const float* opac    = (const float*)d_in[2];
    const float* scales  = (const float*)d_in[3];
    const float* rots    = (const float*)d_in[4];
    const float* campos  = (const float*)d_in[5];
    const float* camrot  = (const float*)d_in[6];
    const float* thf     = (const float*)d_in[7];
    const float* bg      = (const float*)d_in[8];
    const float* nearfar = (const float*)d_in[9];

    char* ws = (char*)d_ws;
    float4* g0 = (float4*)(ws + 0);
    float4* g1 = (float4*)(ws + 16384);
    float4* g2 = (float4*)(ws + 32768);

    k_prep<<<16, 256, 0, stream>>>(means, sh, opac, scales, rots, campos,
                                   camrot, thf, nearfar, g0, g1, g2);
    k_comp<<<256, 1024, 0, stream>>>(g0, g1, g2, bg, (float*)d_out);
}